// Round 6
// baseline (369.696 us; speedup 1.0000x reference)
//
#include <hip/hip_runtime.h>

// BoxFilter: 21x21 all-ones box, circular pad, x: f32[8,1,2048,2048].
// v6: streaming persistent stripes. Each block owns a 512-col x 128-row stripe
// and rolls down rows: colsum[c] += row(r+10) - row(r-11) (old row re-read from
// L2; 21-row working set is L2-resident). Register prefetch rings ldn[7]/ldo[3]
// with compile-time indices (inner loop unrolled exactly 21 deep) keep ~15 KB
// of loads in flight per block. Raw s_barrier + lgkmcnt(0)-only wait: vmcnt is
// NEVER drained, so the prefetch pipeline survives the per-row barrier
// (__syncthreads would emit s_waitcnt vmcnt(0) and kill it).
// LDS: 2 x 536 floats (double-buffered colsum row) = 4.3 KB.

#define HH 2048
#define WW 2048
#define RAD 10
#define DIAM 21
#define TW 512     // output columns per stripe
#define CH 128     // output rows per block
#define NQ 134     // colsum quads: image cols w0-12 .. w0+523
#define SW (NQ * 4)
#define VT 134     // vertical threads (one quad each)
#define HT 128     // horizontal threads (4 output cols each)

typedef float nfloat4 __attribute__((ext_vector_type(4)));

__global__ __launch_bounds__(192) void box_filter_v6(
    const float* __restrict__ x, float* __restrict__ out) {
  __shared__ float sbuf[2][SW];  // double-buffered colsum row

  const int n = blockIdx.z;
  const int r0 = blockIdx.y * CH;
  const int w0 = blockIdx.x * TW;
  const float* __restrict__ xp = x + (size_t)n * (HH * WW);
  float* __restrict__ op = out + (size_t)n * (HH * WW);
  const int t = threadIdx.x;

  // Thread's column quad (circular in W, 16B aligned: w0-12+4t is a mult of 4).
  const int gc = (w0 - 12 + 4 * t) & (WW - 1);
  const float* __restrict__ colp = xp + gc;

#define LOADQ(r) \
  (*(const nfloat4*)(colp + (size_t)(((r) + 2 * HH) & (HH - 1)) * WW))

  nfloat4 colsum = {0.f, 0.f, 0.f, 0.f};
  nfloat4 ldn[7];  // new-row ring: holds rows rr+10 .. rr+16
  nfloat4 ldo[3];  // old-row ring: holds rows rr-11 .. rr-9 (L2 re-reads)

  if (t < VT) {
#pragma unroll
    for (int i = 0; i < 7; ++i) ldn[i] = LOADQ(r0 + 10 + i);
#pragma unroll
    for (int i = 0; i < 3; ++i) ldo[i] = LOADQ(r0 + i - 11);
    // initial colsum covers rows r0-11 .. r0+9 (window state "before row r0")
#pragma unroll
    for (int j = 0; j < DIAM; ++j) colsum += LOADQ(r0 + j - 11);
  }

  bool done = false;
  for (int g = 0; g < 7 && !done; ++g) {  // 7*21 = 147 >= CH
#pragma unroll
    for (int j = 0; j < DIAM; ++j) {
      const int rof = DIAM * g + j;
      if (rof >= CH) { done = true; break; }  // uniform across block
      const int rr = r0 + rof;

      if (t < VT) {
        // consume ring slots (compile-time j%7, j%3 after the 21x unroll),
        // immediately refill with the row needed 7 (resp. 3) rows from now.
        nfloat4 nv = ldn[j % 7];            // row rr+10
        ldn[j % 7] = LOADQ(rr + 17);
        nfloat4 ov = ldo[j % 3];            // row rr-11
        ldo[j % 3] = LOADQ(rr - 8);
        colsum += nv - ov;                  // now covers rr-10 .. rr+10
        *(nfloat4*)&sbuf[rr & 1][4 * t] = colsum;
      }
      // Make ds_writes visible, then barrier WITHOUT draining vmcnt:
      asm volatile("s_waitcnt lgkmcnt(0)" ::: "memory");
      __builtin_amdgcn_s_barrier();

      if (t < HT) {
        // window for output cols w0+4t..+3 is colsum[4t+2 .. 4t+25]
        const float* b = &sbuf[rr & 1][4 * t];
        float w[28];
#pragma unroll
        for (int k = 0; k < 7; ++k)
          *(nfloat4*)&w[4 * k] = *(const nfloat4*)&b[4 * k];
        float s = w[2];
#pragma unroll
        for (int k = 3; k <= 22; ++k) s += w[k];
        nfloat4 o;
        o.x = s;
        s += w[23] - w[2]; o.y = s;
        s += w[24] - w[3]; o.z = s;
        s += w[25] - w[4]; o.w = s;
        *(nfloat4*)&op[(size_t)rr * WW + w0 + 4 * t] = o;
      }
    }
  }
}

extern "C" void kernel_launch(void* const* d_in, const int* in_sizes, int n_in,
                              void* d_out, int out_size, void* d_ws, size_t ws_size,
                              hipStream_t stream) {
  const float* x = (const float*)d_in[0];
  float* out = (float*)d_out;
  dim3 grid(WW / TW, HH / CH, 8);  // 4 x 16 x 8 = 512 blocks (2/CU)
  dim3 block(192);
  hipLaunchKernelGGL(box_filter_v6, grid, block, 0, stream, x, out);
}

// Round 7
// 239.506 us; speedup vs baseline: 1.5436x; 1.5436x over previous
//
#include <hip/hip_runtime.h>

// BoxFilter: 21x21 all-ones box, circular pad, x: f32[8,1,2048,2048].
// v7: async dense staging. The v2..v5 plateau (~3 TB/s) was the compiler
// register-batching the 36-deep per-thread load window (VGPR stuck at 64,
// launch_bounds ignored) -> latency-bound. Fix: stage the raw 52x152 tile to
// LDS with __builtin_amdgcn_global_load_lds (16B, no VGPR round-trip, fully
// async, linear LDS layout as required), then do vertical sliding sums FROM
// LDS, colsums -> padded LDS, horizontal sliding sums -> float4 stores.
// Tile 128x32. LDS 31.6K (raw) + 20K (colsum) = 51.6 KB -> 3 blocks/CU.

#define HH 2048
#define WW 2048
#define RAD 10
#define DIAM 21
#define TH 32
#define TW 128
#define NQ 38                 // quads per raw row: image cols w0-12 .. w0+139
#define RROWS (TH + 20)       // 52 raw rows: h0-10 .. h0+41
#define RQ (RROWS * NQ)       // 1976 raw quads
#define SSTR 156              // colsum row stride (floats); conflict-free ph-B

typedef float nfloat4 __attribute__((ext_vector_type(4)));
typedef const __attribute__((address_space(1))) void* gp_t;
typedef __attribute__((address_space(3))) void* lp_t;

__global__ __launch_bounds__(256) void box_filter_v7(
    const float* __restrict__ x, float* __restrict__ out) {
  __shared__ float sRAW[RQ * 4];      // 31616 B, linear quads: q = r*38 + c
  __shared__ float sCS[TH * SSTR];    // 19968 B: colsum[r][a]

  const int n = blockIdx.z;
  const int h0 = blockIdx.y * TH;
  const int w0 = blockIdx.x * TW;
  const float* __restrict__ xp = x + (size_t)n * (HH * WW);
  float* __restrict__ op = out + (size_t)n * (HH * WW);
  const int tid = threadIdx.x;

  // ---- Stage: 1976 quads, 8 rounds of 256. Per-lane global addr; LDS dest
  // is wave-uniform base + lane*16 (linear, unpadded). No VGPR round-trip.
  {
    const int wbase = tid & ~63;  // wave-uniform within each wave
#pragma unroll
    for (int it = 0; it < 8; ++it) {
      const int idx = it * 256 + tid;          // linear quad index
      if (idx < RQ) {
        const int r = idx / NQ;                // quad row 0..51
        const int c = idx - r * NQ;            // quad col 0..37
        const int grow = (h0 - RAD + r) & (HH - 1);
        const int gcol = (w0 - 12 + 4 * c) & (WW - 1);
        const float* src = xp + (size_t)grow * WW + gcol;
        float* dst = &sRAW[(size_t)(it * 256 + wbase) * 4];
        __builtin_amdgcn_global_load_lds((gp_t)(uintptr_t)src,
                                         (lp_t)(uintptr_t)dst, 16, 0, 0);
      }
    }
  }
  __syncthreads();  // drains vmcnt(0): staged tile complete

  // ---- Phase A: vertical sliding sums from LDS. 38 quad-cols x 2 row-groups
  // = 76 tasks; each slides a 21-tap window down 16 output rows (b128 reads,
  // low register footprint via windowed re-read).
  if (tid < NQ * 2) {
    const int c4 = tid % NQ;
    const int g = tid / NQ;
    const float* base = &sRAW[((16 * g) * NQ + c4) * 4];  // row 16g, quad c4
    nfloat4 s = *(const nfloat4*)base;
#pragma unroll
    for (int k = 1; k < DIAM; ++k)
      s += *(const nfloat4*)(base + k * (NQ * 4));
    *(nfloat4*)&sCS[(16 * g) * SSTR + 4 * c4] = s;
#pragma unroll
    for (int i = 1; i < 16; ++i) {
      s += *(const nfloat4*)(base + (i + 20) * (NQ * 4)) -
           *(const nfloat4*)(base + (i - 1) * (NQ * 4));
      *(nfloat4*)&sCS[(16 * g + i) * SSTR + 4 * c4] = s;
    }
  }
  __syncthreads();

  // ---- Phase B: horizontal sliding sums. 32 rows x 8 chunks = 256 tasks.
  // Window of 40 colsums as 10 b128 (conflict-free at stride 156); output
  // col j sums window[j+2 .. j+22].
  {
    const int r = tid >> 3;              // 0..31
    const int cg = tid & 7;              // 0..7
    const float* row = &sCS[r * SSTR + 16 * cg];
    float* orow = &op[(size_t)(h0 + r) * WW + w0 + 16 * cg];
    __align__(16) float w[40];
#pragma unroll
    for (int k = 0; k < 10; ++k)
      *(nfloat4*)&w[4 * k] = *(const nfloat4*)&row[4 * k];
    float s = w[2];
#pragma unroll
    for (int k = 3; k <= 22; ++k) s += w[k];
    float o[16];
    o[0] = s;
#pragma unroll
    for (int j = 1; j < 16; ++j) {
      s += w[j + 22] - w[j + 1];
      o[j] = s;
    }
#pragma unroll
    for (int q = 0; q < 4; ++q) {
      nfloat4 ov = {o[4 * q], o[4 * q + 1], o[4 * q + 2], o[4 * q + 3]};
      *(nfloat4*)&orow[4 * q] = ov;
    }
  }
}

extern "C" void kernel_launch(void* const* d_in, const int* in_sizes, int n_in,
                              void* d_out, int out_size, void* d_ws, size_t ws_size,
                              hipStream_t stream) {
  const float* x = (const float*)d_in[0];
  float* out = (float*)d_out;
  dim3 grid(WW / TW, HH / TH, 8);  // 16 x 64 x 8 = 8192 blocks
  dim3 block(256);
  hipLaunchKernelGGL(box_filter_v7, grid, block, 0, stream, x, out);
}